// Round 5
// baseline (337.979 us; speedup 1.0000x reference)
//
#include <hip/hip_runtime.h>
#include <cmath>

#define BATCH 128
#define KDIM 1024
#define VOCAB 32001
#define G3 3072
#define NSPLIT 8
#define GIP_STRIDE (BATCH * G3)   // floats per split-K partial

typedef __bf16 bf16_t;
typedef bf16_t bf16x8 __attribute__((ext_vector_type(8)));
typedef float f32x4 __attribute__((ext_vector_type(4)));

// ---------------- async global->LDS (16B/lane, lanes contiguous per wave) ----
__device__ __forceinline__ void stage16(const void* g, void* lds) {
    __builtin_amdgcn_global_load_lds(
        (const __attribute__((address_space(1))) void*)g,
        (__attribute__((address_space(3))) void*)lds, 16, 0, 0);
}

// online-softmax merge: (m,s) <- merge((m,s),(mo,so))
__device__ __forceinline__ void smerge(float& m, float& s, float mo, float so) {
    const float mn = fmaxf(m, mo);
    s = s * __expf(m - mn) + so * __expf(mo - mn);
    m = mn;
}

// ================= GRU GEMM: BM=128, BN=64, BK=64, split-K=8 =================
// sA bf16 [128][64]: row=128B=8 granules, phys g = logical ^ (row&7)
// sB f32  [64][64]:  row=256B=16 granules, phys g = logical ^ (row&15)
__global__ __launch_bounds__(256, 4) void gemm_gru(
    const bf16_t* __restrict__ Ai, const float* __restrict__ wih,
    float* __restrict__ giP,
    const bf16_t* __restrict__ Ah, const float* __restrict__ whh,
    float* __restrict__ ghP)
{
    const int split = blockIdx.x;           // 0..7 -> K range [split*128, +128)
    const int n0    = blockIdx.y * 64;
    const int kbeg  = split * 128;
    const bf16_t* A; const float* W; float* C;
    if (blockIdx.z == 0) { A = Ai; W = wih; C = giP + (size_t)split * GIP_STRIDE; }
    else                 { A = Ah; W = whh; C = ghP + (size_t)split * GIP_STRIDE; }

    __shared__ bf16_t sA[128 * 64];   // 16 KB
    __shared__ float  sB[64 * 64];    // 16 KB
    const int t    = threadIdx.x;
    const int wave = t >> 6;
    const int lane = t & 63;
    const int l15  = lane & 15;
    const int quad = lane >> 4;
    const int wm   = wave & 1;
    const int wn   = wave >> 1;

    const bf16_t* aSrc[4]; int aDst[4];
#pragma unroll
    for (int r = 0; r < 4; ++r) {
        const int row = r * 32 + (t >> 3);
        const int sg  = t & 7;
        aSrc[r] = A + (size_t)row * KDIM + (sg ^ (row & 7)) * 8 + kbeg;
        aDst[r] = row * 128 + sg * 16;
    }
    const float* wSrc[4]; int wDst[4];
#pragma unroll
    for (int r = 0; r < 4; ++r) {
        const int row = r * 16 + (t >> 4);
        const int sg  = t & 15;
        wSrc[r] = W + (size_t)(n0 + row) * KDIM + (sg ^ (row & 15)) * 4 + kbeg;
        wDst[r] = row * 256 + sg * 16;
    }

    f32x4 acc[4][2];
#pragma unroll
    for (int i = 0; i < 4; ++i)
#pragma unroll
        for (int j = 0; j < 2; ++j) acc[i][j] = f32x4{0.f, 0.f, 0.f, 0.f};

#pragma unroll
    for (int k0 = 0; k0 < 128; k0 += 64) {
#pragma unroll
        for (int r = 0; r < 4; ++r) stage16(aSrc[r] + k0, (char*)sA + aDst[r]);
#pragma unroll
        for (int r = 0; r < 4; ++r) stage16(wSrc[r] + k0, (char*)sB + wDst[r]);
        __syncthreads();
#pragma unroll
        for (int s = 0; s < 2; ++s) {
            bf16x8 bfr[2];
#pragma unroll
            for (int j = 0; j < 2; ++j) {
                const int row = wn * 32 + j * 16 + l15;
                const int gu  = (s * 8 + 2 * quad) ^ (row & 15);
                const f32x4 u = *(const f32x4*)((const char*)sB + row * 256 + gu * 16);
                const f32x4 v = *(const f32x4*)((const char*)sB + row * 256 + (gu ^ 1) * 16);
                bf16x8 b;
                b[0] = (bf16_t)u[0]; b[1] = (bf16_t)u[1]; b[2] = (bf16_t)u[2]; b[3] = (bf16_t)u[3];
                b[4] = (bf16_t)v[0]; b[5] = (bf16_t)v[1]; b[6] = (bf16_t)v[2]; b[7] = (bf16_t)v[3];
                bfr[j] = b;
            }
#pragma unroll
            for (int i = 0; i < 4; ++i) {
                const int row  = wm * 64 + i * 16 + l15;
                const int phys = (s * 4 + quad) ^ (row & 7);
                const bf16x8 af = *(const bf16x8*)((const char*)sA + row * 128 + phys * 16);
#pragma unroll
                for (int j = 0; j < 2; ++j)
                    acc[i][j] = __builtin_amdgcn_mfma_f32_16x16x32_bf16(
                        af, bfr[j], acc[i][j], 0, 0, 0);
            }
        }
        __syncthreads();
    }

#pragma unroll
    for (int j = 0; j < 2; ++j) {
        const int col = n0 + wn * 32 + j * 16 + l15;
#pragma unroll
        for (int i = 0; i < 4; ++i)
#pragma unroll
            for (int r = 0; r < 4; ++r) {
                const int row = wm * 64 + i * 16 + quad * 4 + r;
                C[(size_t)row * G3 + col] = acc[i][j][r];
            }
    }
}

// ================= Vocab GEMM: BM=128, BN=64, BK=128, fused softmax stats ====
// sA bf16 [128][128]: row=256B=16 granules, phys = logical ^ (row&7)
// sB f32  [64][128]:  row=512B=32 granules, phys = logical ^ (row&7)
__global__ __launch_bounds__(256, 2) void gemm_vocab(
    const bf16_t* __restrict__ A, const float* __restrict__ W,
    const float* __restrict__ bias, float* __restrict__ C,
    float2* __restrict__ stats)
{
    __shared__ bf16_t sA[128 * 128];  // 32 KB
    __shared__ float  sB[64 * 128];   // 32 KB
    const int t    = threadIdx.x;
    const int wave = t >> 6;
    const int lane = t & 63;
    const int l15  = lane & 15;
    const int quad = lane >> 4;
    const int wm   = wave & 1;
    const int wn   = wave >> 1;
    const int n0   = blockIdx.x * 64;

    const bf16_t* aSrc[8]; int aDst[8];
#pragma unroll
    for (int r = 0; r < 8; ++r) {
        const int row = r * 16 + (t >> 4);
        const int sg  = t & 15;
        aSrc[r] = A + (size_t)row * KDIM + (sg ^ (row & 7)) * 8;
        aDst[r] = row * 256 + sg * 16;
    }
    const float* wSrc[8]; int wDst[8];
#pragma unroll
    for (int r = 0; r < 8; ++r) {
        const int row = r * 8 + (t >> 5);
        int wr = n0 + row; if (wr > VOCAB - 1) wr = VOCAB - 1;
        const int sg = t & 31;
        wSrc[r] = W + (size_t)wr * KDIM + (sg ^ (row & 7)) * 4;
        wDst[r] = row * 512 + sg * 16;
    }

    f32x4 acc[4][2];
#pragma unroll
    for (int i = 0; i < 4; ++i)
#pragma unroll
        for (int j = 0; j < 2; ++j) acc[i][j] = f32x4{0.f, 0.f, 0.f, 0.f};

    for (int k0 = 0; k0 < KDIM; k0 += 128) {
#pragma unroll
        for (int r = 0; r < 8; ++r) stage16(aSrc[r] + k0, (char*)sA + aDst[r]);
#pragma unroll
        for (int r = 0; r < 8; ++r) stage16(wSrc[r] + k0, (char*)sB + wDst[r]);
        __syncthreads();
#pragma unroll
        for (int s = 0; s < 4; ++s) {
            bf16x8 bfr[2];
#pragma unroll
            for (int j = 0; j < 2; ++j) {
                const int row = wn * 32 + j * 16 + l15;
                const int g0  = s * 8 + quad * 2;
                const int p0  = g0 ^ (row & 7);
                const int p1  = (g0 + 1) ^ (row & 7);
                const f32x4 u = *(const f32x4*)((const char*)sB + row * 512 + p0 * 16);
                const f32x4 v = *(const f32x4*)((const char*)sB + row * 512 + p1 * 16);
                bf16x8 b;
                b[0] = (bf16_t)u[0]; b[1] = (bf16_t)u[1]; b[2] = (bf16_t)u[2]; b[3] = (bf16_t)u[3];
                b[4] = (bf16_t)v[0]; b[5] = (bf16_t)v[1]; b[6] = (bf16_t)v[2]; b[7] = (bf16_t)v[3];
                bfr[j] = b;
            }
#pragma unroll
            for (int i = 0; i < 4; ++i) {
                const int row  = wm * 64 + i * 16 + l15;
                const int phys = (s * 4 + quad) ^ (row & 7);
                const bf16x8 af = *(const bf16x8*)((const char*)sA + row * 256 + phys * 16);
#pragma unroll
                for (int j = 0; j < 2; ++j)
                    acc[i][j] = __builtin_amdgcn_mfma_f32_16x16x32_bf16(
                        af, bfr[j], acc[i][j], 0, 0, 0);
            }
        }
        __syncthreads();
    }

    // -------- epilogue: biased store + per-row online (m,s) over 64 cols -----
    int   col[2]; float bv[2];
#pragma unroll
    for (int j = 0; j < 2; ++j) {
        col[j] = n0 + wn * 32 + j * 16 + l15;
        bv[j]  = (col[j] < VOCAB) ? bias[col[j]] : 0.f;
    }
    float rm[4][4], rs[4][4];
#pragma unroll
    for (int i = 0; i < 4; ++i)
#pragma unroll
        for (int r = 0; r < 4; ++r) {
            const int grow = wm * 64 + i * 16 + quad * 4 + r;
            float v0 = acc[i][0][r] + bv[0];
            float v1 = acc[i][1][r] + bv[1];
            if (col[0] < VOCAB) C[(size_t)grow * VOCAB + col[0]] = v0; else v0 = -3.4e38f;
            if (col[1] < VOCAB) C[(size_t)grow * VOCAB + col[1]] = v1; else v1 = -3.4e38f;
            const float mm = fmaxf(v0, v1);
            rm[i][r] = mm;
            rs[i][r] = __expf(v0 - mm) + __expf(v1 - mm);
#pragma unroll
            for (int o = 1; o < 16; o <<= 1)
                smerge(rm[i][r], rs[i][r], __shfl_xor(rm[i][r], o), __shfl_xor(rs[i][r], o));
        }

    __syncthreads();                       // sA free for reuse
    float2* sst = (float2*)sA;             // [2 wn][128 rows]
#pragma unroll
    for (int i = 0; i < 4; ++i)
#pragma unroll
        for (int r = 0; r < 4; ++r)
            if (l15 == 0)
                sst[wn * 128 + wm * 64 + i * 16 + quad * 4 + r] =
                    make_float2(rm[i][r], rs[i][r]);
    __syncthreads();
    if (t < 128) {
        float2 a = sst[t], b = sst[128 + t];
        smerge(a.x, a.y, b.x, b.y);
        stats[(size_t)t * 512 + blockIdx.x] = a;
    }
}

// ---------------- prep: x=relu(emb[idx]) -> bf16; hidden[0/1] -> bf16 --------
__global__ __launch_bounds__(256) void prep_bf16(const int* __restrict__ idx,
                                                 const float* __restrict__ emb,
                                                 const float* __restrict__ hidden,
                                                 bf16_t* __restrict__ dst) {
    const int i = blockIdx.x * 256 + threadIdx.x;   // 0..98303 (f32x4 groups)
    const int sec = i >> 15;                        // 0:x 1:hp0 2:hp1
    const int j   = i & 32767;
    f32x4 v;
    if (sec == 0) {
        const int b = j >> 8, e4 = j & 255;
        v = ((const f32x4*)(emb + (size_t)idx[b] * KDIM))[e4];
#pragma unroll
        for (int k = 0; k < 4; ++k) v[k] = fmaxf(v[k], 0.f);
    } else {
        v = ((const f32x4*)(hidden + (size_t)(sec - 1) * (BATCH * KDIM)))[j];
    }
    bf16_t o[4];
#pragma unroll
    for (int k = 0; k < 4; ++k) o[k] = (bf16_t)v[k];
    *(uint64_t*)(dst + (size_t)i * 4) = *(const uint64_t*)o;
}

// ---------------- gate: sum 8 split-K partials + biases + GRU math -----------
__device__ __forceinline__ f32x4 sum_splits(const float* p) {
    f32x4 s = *(const f32x4*)p;
#pragma unroll
    for (int k = 1; k < NSPLIT; ++k) s += *(const f32x4*)(p + (size_t)k * GIP_STRIDE);
    return s;
}

__global__ __launch_bounds__(128) void gru_gate(const float* __restrict__ giP,
                                                const float* __restrict__ ghP,
                                                const float* __restrict__ b_ih,
                                                const float* __restrict__ b_hh,
                                                const float* __restrict__ hprev,
                                                float* __restrict__ hout,
                                                bf16_t* __restrict__ hout_bf16) {
    const int i  = blockIdx.x * 128 + threadIdx.x;  // 0..32767
    const int b  = i >> 8;
    const int j  = (i & 255) * 4;
    const size_t base = (size_t)b * G3 + j;

    f32x4 ir = sum_splits(giP + base),        hr = sum_splits(ghP + base);
    f32x4 iz = sum_splits(giP + base + 1024), hz = sum_splits(ghP + base + 1024);
    f32x4 in = sum_splits(giP + base + 2048), hn = sum_splits(ghP + base + 2048);
    const f32x4 bir = *(const f32x4*)(b_ih + j);
    const f32x4 biz = *(const f32x4*)(b_ih + j + 1024);
    const f32x4 bin = *(const f32x4*)(b_ih + j + 2048);
    const f32x4 bhr = *(const f32x4*)(b_hh + j);
    const f32x4 bhz = *(const f32x4*)(b_hh + j + 1024);
    const f32x4 bhn = *(const f32x4*)(b_hh + j + 2048);
    const f32x4 hp  = *(const f32x4*)(hprev + (size_t)b * KDIM + j);

    f32x4 o;
    bf16_t ob[4];
#pragma unroll
    for (int k = 0; k < 4; ++k) {
        const float r = 1.f / (1.f + __expf(-(ir[k] + bir[k] + hr[k] + bhr[k])));
        const float z = 1.f / (1.f + __expf(-(iz[k] + biz[k] + hz[k] + bhz[k])));
        const float a = in[k] + bin[k] + r * (hn[k] + bhn[k]);
        const float n = 1.f - 2.f / (__expf(2.f * a) + 1.f);   // tanh
        o[k] = (1.f - z) * n + z * hp[k];
        ob[k] = (bf16_t)o[k];
    }
    *(f32x4*)(hout + (size_t)b * KDIM + j) = o;
    *(uint64_t*)(hout_bf16 + (size_t)b * KDIM + j) = *(const uint64_t*)ob;
}

// ---------------- softmax finalize: reduce 501 stats per row, subtract -------
__global__ __launch_bounds__(256) void softmax_final(float* __restrict__ out,
                                                     const float2* __restrict__ stats) {
    const int row = blockIdx.x, chunk = blockIdx.y, t = threadIdx.x;
    float m = -3.4e38f, s = 0.f;
    for (int k = t; k < 501; k += 256) {
        const float2 p = stats[(size_t)row * 512 + k];
        smerge(m, s, p.x, p.y);
    }
#pragma unroll
    for (int o = 32; o; o >>= 1) {
        const float mo = __shfl_down(m, o);
        const float so = __shfl_down(s, o);
        smerge(m, s, mo, so);
    }
    __shared__ float sm[4], ssu[4], sL;
    if ((t & 63) == 0) { sm[t >> 6] = m; ssu[t >> 6] = s; }
    __syncthreads();
    if (t == 0) {
        float M = sm[0], S = ssu[0];
#pragma unroll
        for (int w = 1; w < 4; ++w) smerge(M, S, sm[w], ssu[w]);
        sL = M + __logf(S);
    }
    __syncthreads();
    const float L = sL;

    float* rowp = out + (size_t)row * VOCAB;
    const int g = chunk * 256 + t;    // 0..1023
    for (int i = g * 4; i + 3 < VOCAB; i += 4096) {
        f32x4 v = *(const f32x4*)(rowp + i);
        v[0] -= L; v[1] -= L; v[2] -= L; v[3] -= L;
        *(f32x4*)(rowp + i) = v;
    }
    if (g == 0) rowp[32000] -= L;
}

// ---------------- launch -----------------------------------------------------
extern "C" void kernel_launch(void* const* d_in, const int* in_sizes, int n_in,
                              void* d_out, int out_size, void* d_ws, size_t ws_size,
                              hipStream_t stream) {
    const int*   ivec  = (const int*)  d_in[0];
    const float* hidden= (const float*)d_in[1];
    const float* emb   = (const float*)d_in[2];
    const float* w_ih0 = (const float*)d_in[3];
    const float* w_hh0 = (const float*)d_in[4];
    const float* b_ih0 = (const float*)d_in[5];
    const float* b_hh0 = (const float*)d_in[6];
    const float* w_ih1 = (const float*)d_in[7];
    const float* w_hh1 = (const float*)d_in[8];
    const float* b_ih1 = (const float*)d_in[9];
    const float* b_hh1 = (const float*)d_in[10];
    const float* w_out = (const float*)d_in[11];
    const float* b_out = (const float*)d_in[12];

    float* out = (float*)d_out;
    float* h0  = out + (size_t)BATCH * VOCAB;   // hidden_out[0] (fp32)
    float* h1  = h0 + BATCH * KDIM;             // hidden_out[1] (fp32)

    // d_ws layout
    float*  ws    = (float*)d_ws;
    float*  giP   = ws;                                   // [8][128][3072] f32
    float*  ghP   = ws + (size_t)NSPLIT * GIP_STRIDE;     // [8][128][3072] f32
    bf16_t* xb    = (bf16_t*)(ws + 2 * (size_t)NSPLIT * GIP_STRIDE);
    bf16_t* hp0b  = xb   + BATCH * KDIM;
    bf16_t* hp1b  = hp0b + BATCH * KDIM;
    bf16_t* h0b   = hp1b + BATCH * KDIM;
    bf16_t* h1b   = h0b  + BATCH * KDIM;
    float2* stats = (float2*)(h1b + BATCH * KDIM);        // [128][512]

    const float* hprev0 = hidden;
    const float* hprev1 = hidden + BATCH * KDIM;

    prep_bf16<<<384, 256, 0, stream>>>(ivec, emb, hidden, xb);

    gemm_gru<<<dim3(8, 48, 2), 256, 0, stream>>>(xb, w_ih0, giP, hp0b, w_hh0, ghP);
    gru_gate<<<256, 128, 0, stream>>>(giP, ghP, b_ih0, b_hh0, hprev0, h0, h0b);

    gemm_gru<<<dim3(8, 48, 2), 256, 0, stream>>>(h0b, w_ih1, giP, hp1b, w_hh1, ghP);
    gru_gate<<<256, 128, 0, stream>>>(giP, ghP, b_ih1, b_hh1, hprev1, h1, h1b);

    gemm_vocab<<<501, 256, 0, stream>>>(h1b, w_out, b_out, out, stats);

    softmax_final<<<dim3(128, 4), 256, 0, stream>>>(out, stats);
}